// Round 1
// baseline (518.350 us; speedup 1.0000x reference)
//
#include <hip/hip_runtime.h>
#include <math.h>

#define NB 64
#define NP 8396
#define NK 6
#define NC 25
#define NPR 3   // NEG_POS_RATIO

// order-preserving float->uint map (for radix select of T-th largest)
__device__ inline unsigned fmap(float f){
    unsigned b = __float_as_uint(f);
    return (b & 0x80000000u) ? ~b : (b | 0x80000000u);
}
// -inf maps to 0x007FFFFF; all finite mining scores map strictly above it.

// ---------------- Kernel A: IoU per (b,p), init scalar accumulators ----------------
__global__ __launch_bounds__(256) void k_iou(
    const float* __restrict__ prior, const float* __restrict__ gtr,
    float* __restrict__ iou,
    int* __restrict__ Ntot, int* __restrict__ selc,
    float* __restrict__ llsum, float* __restrict__ cesum)
{
    int idx = blockIdx.x * 256 + threadIdx.x;
    if (idx == 0) { *Ntot = 0; *selc = 0; *llsum = 0.f; *cesum = 0.f; }
    if (idx >= NB * NP) return;
    int b = idx / NP;
    int p = idx - b * NP;
    const float* pr = prior + p * (4 * NK);
    const float* gt = gtr + b * (1 + 4 * NK) + 1;
    float csum = 0.f, fsum = 0.f;
#pragma unroll
    for (int k = 0; k < NK; k++) {
        float px0 = pr[4*k+0], py0 = pr[4*k+1], px1 = pr[4*k+2], py1 = pr[4*k+3];
        float gx0 = gt[4*k+0], gy0 = gt[4*k+1], gx1 = gt[4*k+2], gy1 = gt[4*k+3];
        float ix = fminf(px1, gx1) - fmaxf(px0, gx0);
        float iy = fminf(py1, gy1) - fmaxf(py0, gy0);
        float cross = fmaxf(ix, 0.f) * fmaxf(iy, 0.f);
        float pa = (px1 - px0) * (py1 - py0);
        float ga = (gx1 - gx0) * (gy1 - gy0);
        csum += cross;
        fsum += cross / (ga + pa - cross);
    }
    iou[idx] = (csum > 0.f) ? (fsum / (float)NK) : 0.f;
}

// ---------------- Kernel B: per-batch argmax (first-index tie-break) + npos ----------------
__global__ __launch_bounds__(256) void k_argmax(
    const float* __restrict__ iou,
    int* __restrict__ best, int* __restrict__ npos, int* __restrict__ Ntot)
{
    int b = blockIdx.x, tid = threadIdx.x;
    const float* row = iou + (size_t)b * NP;
    __shared__ float smax[256];
    __shared__ int   sidx[256];
    __shared__ int   scnt[256];
    float mv = -INFINITY; int mi = 0x7FFFFFFF;
    for (int p = tid; p < NP; p += 256) {
        float v = row[p];
        if (v > mv || (v == mv && p < mi)) { mv = v; mi = p; }
    }
    smax[tid] = mv; sidx[tid] = mi;
    __syncthreads();
    for (int s = 128; s > 0; s >>= 1) {
        if (tid < s) {
            if (smax[tid+s] > smax[tid] ||
                (smax[tid+s] == smax[tid] && sidx[tid+s] < sidx[tid])) {
                smax[tid] = smax[tid+s]; sidx[tid] = sidx[tid+s];
            }
        }
        __syncthreads();
    }
    int bst = sidx[0];
    // count iou >= 0.5
    int c = 0;
    for (int p = tid; p < NP; p += 256) c += (row[p] >= 0.5f) ? 1 : 0;
    scnt[tid] = c;
    __syncthreads();
    for (int s = 128; s > 0; s >>= 1) {
        if (tid < s) scnt[tid] += scnt[tid+s];
        __syncthreads();
    }
    if (tid == 0) {
        int np = scnt[0] + ((row[bst] >= 0.5f) ? 0 : 1);
        best[b] = bst;
        npos[b] = np;
        atomicAdd(Ntot, np);
    }
}

// ---------------- Kernel C: softmax CE + mining score + smooth-L1 for positives ----------------
__global__ __launch_bounds__(256) void k_conf(
    const float* __restrict__ loc, const float* __restrict__ conf,
    const float* __restrict__ prior, const float* __restrict__ gtr,
    const float* __restrict__ iou, const int* __restrict__ best,
    unsigned* __restrict__ u, float* __restrict__ ce, float* __restrict__ llsum)
{
    int idx = blockIdx.x * 256 + threadIdx.x;
    if (idx >= NB * NP) return;
    int b = idx / NP;
    int p = idx - b * NP;
    bool pos = (iou[idx] >= 0.5f) || (p == best[b]);
    int cls = (int)gtr[b * (1 + 4 * NK)];     // gt class, 1..C-1
    int tgt = pos ? cls : 0;

    const float* cf = conf + (size_t)idx * NC;
    float m = cf[0];
#pragma unroll
    for (int c = 1; c < NC; c++) m = fmaxf(m, cf[c]);
    float s = 0.f;
#pragma unroll
    for (int c = 0; c < NC; c++) s += expf(cf[c] - m);
    float xt = cf[tgt];
    float cev = m + logf(s) - xt;             // -log_softmax[target]
    ce[idx] = cev;
    float pt = expf(xt - m) / s;              // softmax[target]
    float tl = -logf(pt + 1e-6f);             // mining score
    u[idx] = pos ? 0x007FFFFFu : fmap(tl);    // pos -> map(-inf)

    if (pos) {
        const float* pr = prior + p * (4 * NK);
        const float* gt = gtr + b * (1 + 4 * NK) + 1;
        const float* lp = loc + (size_t)idx * (4 * NK);
        float sum = 0.f;
#pragma unroll
        for (int k = 0; k < NK; k++) {
            float px0 = pr[4*k+0], py0 = pr[4*k+1], px1 = pr[4*k+2], py1 = pr[4*k+3];
            float gx0 = gt[4*k+0], gy0 = gt[4*k+1], gx1 = gt[4*k+2], gy1 = gt[4*k+3];
            float pcx = (px0 + px1) * 0.5f, pcy = (py0 + py1) * 0.5f;
            float pw = px1 - px0, ph = py1 - py0;
            float gcx = (gx0 + gx1) * 0.5f, gcy = (gy0 + gy1) * 0.5f;
            float gw = gx1 - gx0, gh = gy1 - gy0;
            float e0 = ((gcx - pcx) / pw) / 0.1f;
            float e1 = ((gcy - pcy) / ph) / 0.1f;
            float e2 = logf(gw / pw) / 0.2f;
            float e3 = logf(gh / ph) / 0.2f;
            float d;
            d = fabsf(lp[4*k+0] - e0); sum += (d < 1.f) ? 0.5f*d*d : d - 0.5f;
            d = fabsf(lp[4*k+1] - e1); sum += (d < 1.f) ? 0.5f*d*d : d - 0.5f;
            d = fabsf(lp[4*k+2] - e2); sum += (d < 1.f) ? 0.5f*d*d : d - 0.5f;
            d = fabsf(lp[4*k+3] - e3); sum += (d < 1.f) ? 0.5f*d*d : d - 0.5f;
        }
        atomicAdd(llsum, sum);
    }
}

// ---------------- Kernel D: per-batch radix top-T select + CE sum over selected ----------------
__global__ __launch_bounds__(256) void k_select(
    const unsigned* __restrict__ u, const float* __restrict__ ce,
    const float* __restrict__ iou, const int* __restrict__ best,
    const int* __restrict__ npos,
    float* __restrict__ cesum, int* __restrict__ selc)
{
    int b = blockIdx.x, tid = threadIdx.x;
    const unsigned* ub = u + (size_t)b * NP;
    const float* ceb = ce + (size_t)b * NP;
    const float* ioub = iou + (size_t)b * NP;
    int np = npos[b];
    int T = NPR * np;
    int maxneg = NP - np;
    if (T > maxneg) T = maxneg;

    __shared__ int scnt[256];
    __shared__ float ssum[256];
    __shared__ unsigned sprefix;
    __shared__ int sremain;
    if (tid == 0) { sprefix = 0u; sremain = T; }
    __syncthreads();

    // 32-step radix select for the T-th largest u (T >= 3 always since npos >= 1)
    for (int bit = 31; bit >= 0; --bit) {
        unsigned pref = sprefix;
        unsigned bitm = 1u << bit;
        unsigned himask = ~((bitm << 1) - 1u);   // bits above current (wraps to 0 at bit=31)
        int c = 0;
        for (int p = tid; p < NP; p += 256) {
            unsigned v = ub[p];
            if (((v & himask) == pref) && (v & bitm)) c++;
        }
        scnt[tid] = c;
        __syncthreads();
        for (int s = 128; s > 0; s >>= 1) {
            if (tid < s) scnt[tid] += scnt[tid+s];
            __syncthreads();
        }
        if (tid == 0) {
            int cnt = scnt[0];
            if (cnt >= sremain) sprefix = pref | bitm;
            else sremain -= cnt;
        }
        __syncthreads();
    }
    unsigned thr = sprefix;
    int needed = sremain;   // #ties (u == thr) to take, in ascending index order

    int bst = best[b];
    float sum = 0.f;
    for (int p = tid; p < NP; p += 256) {
        unsigned v = ub[p];
        bool pos = (ioub[p] >= 0.5f) || (p == bst);
        if (pos) {
            sum += ceb[p];
        } else if (v > thr) {
            sum += ceb[p];
        } else if (v == thr) {
            // stable argsort tie semantics: earlier index wins (rare path)
            int r = 0;
            for (int q = 0; q < p; q++) if (ub[q] == thr) r++;
            if (r < needed) sum += ceb[p];
        }
    }
    ssum[tid] = sum;
    __syncthreads();
    for (int s = 128; s > 0; s >>= 1) {
        if (tid < s) ssum[tid] += ssum[tid+s];
        __syncthreads();
    }
    if (tid == 0) {
        atomicAdd(cesum, ssum[0]);
        atomicAdd(selc, np + T);   // exactly T negs selected + np positives
    }
}

// ---------------- Kernel E: finalize ----------------
__global__ void k_final(const float* __restrict__ llsum, const int* __restrict__ Ntot,
                        const float* __restrict__ cesum, const int* __restrict__ selc,
                        float* __restrict__ out)
{
    if (blockIdx.x == 0 && threadIdx.x == 0) {
        out[0] = llsum[0] / (float)NK / (float)Ntot[0];
        out[1] = cesum[0] / (float)selc[0];
    }
}

extern "C" void kernel_launch(void* const* d_in, const int* in_sizes, int n_in,
                              void* d_out, int out_size, void* d_ws, size_t ws_size,
                              hipStream_t stream)
{
    const float* loc   = (const float*)d_in[0];
    const float* conf  = (const float*)d_in[1];
    const float* prior = (const float*)d_in[2];
    const float* gtr   = (const float*)d_in[3];
    float* out = (float*)d_out;

    char* w = (char*)d_ws;
    size_t bp = (size_t)NB * NP;
    float*    iou   = (float*)w;    w += bp * sizeof(float);
    unsigned* u     = (unsigned*)w; w += bp * sizeof(unsigned);
    float*    ce    = (float*)w;    w += bp * sizeof(float);
    int*      best  = (int*)w;      w += NB * sizeof(int);
    int*      npos  = (int*)w;      w += NB * sizeof(int);
    int*      Ntot  = (int*)w;      w += sizeof(int);
    int*      selc  = (int*)w;      w += sizeof(int);
    float*    llsum = (float*)w;    w += sizeof(float);
    float*    cesum = (float*)w;    w += sizeof(float);

    int nblk = (NB * NP + 255) / 256;
    k_iou   <<<nblk, 256, 0, stream>>>(prior, gtr, iou, Ntot, selc, llsum, cesum);
    k_argmax<<<NB,   256, 0, stream>>>(iou, best, npos, Ntot);
    k_conf  <<<nblk, 256, 0, stream>>>(loc, conf, prior, gtr, iou, best, u, ce, llsum);
    k_select<<<NB,   256, 0, stream>>>(u, ce, iou, best, npos, cesum, selc);
    k_final <<<1,    64,  0, stream>>>(llsum, Ntot, cesum, selc, out);
}

// Round 2
// 158.891 us; speedup vs baseline: 3.2623x; 3.2623x over previous
//
#include <hip/hip_runtime.h>
#include <math.h>

#define NB 64
#define NP 8396
#define NK 6
#define NC 25
#define NPR 3            // NEG_POS_RATIO
#define MARKER 0x007FFFFFu   // fmap(-inf): positives' mining key; all real (finite) scores map strictly above

// order-preserving float->uint map (for selecting the T-th largest)
__device__ inline unsigned fmap(float f){
    unsigned b = __float_as_uint(f);
    return (b & 0x80000000u) ? ~b : (b | 0x80000000u);
}

// ---------------- Kernel A: IoU per (b,p) + fused per-batch argmax/count ----------------
// grid = (ceil(NP/256), NB); packed[b] = max over p of (iou_bits<<32 | ~p)  -> max iou, min index
__global__ __launch_bounds__(256) void k_iou(
    const float* __restrict__ prior, const float* __restrict__ gtr,
    float* __restrict__ iou,
    unsigned long long* __restrict__ packed, int* __restrict__ cnt)
{
    int b = blockIdx.y;
    int p = blockIdx.x * 256 + threadIdx.x;
    bool valid = p < NP;
    float v = 0.f;
    if (valid) {
        const float* pr = prior + p * (4 * NK);
        const float* gt = gtr + b * (1 + 4 * NK) + 1;
        float csum = 0.f, fsum = 0.f;
#pragma unroll
        for (int k = 0; k < NK; k++) {
            float px0 = pr[4*k+0], py0 = pr[4*k+1], px1 = pr[4*k+2], py1 = pr[4*k+3];
            float gx0 = gt[4*k+0], gy0 = gt[4*k+1], gx1 = gt[4*k+2], gy1 = gt[4*k+3];
            float ix = fminf(px1, gx1) - fmaxf(px0, gx0);
            float iy = fminf(py1, gy1) - fmaxf(py0, gy0);
            float cross = fmaxf(ix, 0.f) * fmaxf(iy, 0.f);
            float pa = (px1 - px0) * (py1 - py0);
            float ga = (gx1 - gx0) * (gy1 - gy0);
            csum += cross;
            fsum += cross / (ga + pa - cross);
        }
        v = (csum > 0.f) ? (fsum * (1.f / (float)NK)) : 0.f;
        iou[(size_t)b * NP + p] = v;
    }
    // iou >= 0 so float bits are monotone; invalid lanes contribute 0 (minimal)
    unsigned long long pk = valid
        ? (((unsigned long long)__float_as_uint(v) << 32) | (unsigned long long)(0xFFFFFFFFu - (unsigned)p))
        : 0ULL;
#pragma unroll
    for (int o = 32; o > 0; o >>= 1) {
        unsigned long long other = __shfl_down(pk, o);
        if (other > pk) pk = other;
    }
    unsigned long long bal = __ballot(valid && v >= 0.5f);
    __shared__ unsigned long long wpk[4];
    __shared__ int wcnt[4];
    int lane = threadIdx.x & 63, wv = threadIdx.x >> 6;
    if (lane == 0) { wpk[wv] = pk; wcnt[wv] = __popcll(bal); }
    __syncthreads();
    if (threadIdx.x == 0) {
        unsigned long long m = wpk[0]; int c = wcnt[0];
#pragma unroll
        for (int i = 1; i < 4; i++) { if (wpk[i] > m) m = wpk[i]; c += wcnt[i]; }
        atomicMax(&packed[b], m);
        if (c) atomicAdd(&cnt[b], c);
    }
}

// ---------------- Kernel B: unpack best, compute npos and Ntot (1 wave) ----------------
__global__ void k_mini(
    const unsigned long long* __restrict__ packed, const int* __restrict__ cnt,
    const float* __restrict__ iou,
    int* __restrict__ best, int* __restrict__ npos, int* __restrict__ Ntot)
{
    int b = threadIdx.x;   // 64 threads = NB
    unsigned long long pk = packed[b];
    int bst = (int)(0xFFFFFFFFu - (unsigned)(pk & 0xFFFFFFFFULL));
    int np = cnt[b] + ((iou[(size_t)b * NP + bst] >= 0.5f) ? 0 : 1);
    best[b] = bst;
    npos[b] = np;
    int s = np;
#pragma unroll
    for (int o = 32; o > 0; o >>= 1) s += __shfl_down(s, o);
    if (b == 0) *Ntot = s;
}

// ---------------- Kernel C: softmax CE + mining key + smooth-L1 for positives ----------------
__global__ __launch_bounds__(256) void k_conf(
    const float* __restrict__ loc, const float* __restrict__ conf,
    const float* __restrict__ prior, const float* __restrict__ gtr,
    const float* __restrict__ iou, const int* __restrict__ best,
    unsigned* __restrict__ u, float* __restrict__ ce, float* __restrict__ llsum)
{
    int b = blockIdx.y;
    int p = blockIdx.x * 256 + threadIdx.x;
    if (p >= NP) return;
    size_t idx = (size_t)b * NP + p;
    bool pos = (iou[idx] >= 0.5f) || (p == best[b]);
    int cls = (int)gtr[b * (1 + 4 * NK)];
    int tgt = pos ? cls : 0;

    const float* cf = conf + idx * NC;
    float m = cf[0];
#pragma unroll
    for (int c = 1; c < NC; c++) m = fmaxf(m, cf[c]);
    float s = 0.f;
#pragma unroll
    for (int c = 0; c < NC; c++) s += expf(cf[c] - m);
    float xt = cf[tgt];
    float cev = m + logf(s) - xt;
    ce[idx] = cev;
    float pt = expf(xt - m) / s;
    float tl = -logf(pt + 1e-6f);
    u[idx] = pos ? MARKER : fmap(tl);

    if (pos) {
        const float* pr = prior + p * (4 * NK);
        const float* gt = gtr + b * (1 + 4 * NK) + 1;
        const float* lp = loc + idx * (4 * NK);
        float sum = 0.f;
#pragma unroll
        for (int k = 0; k < NK; k++) {
            float px0 = pr[4*k+0], py0 = pr[4*k+1], px1 = pr[4*k+2], py1 = pr[4*k+3];
            float gx0 = gt[4*k+0], gy0 = gt[4*k+1], gx1 = gt[4*k+2], gy1 = gt[4*k+3];
            float pcx = (px0 + px1) * 0.5f, pcy = (py0 + py1) * 0.5f;
            float pw = px1 - px0, ph = py1 - py0;
            float gcx = (gx0 + gx1) * 0.5f, gcy = (gy0 + gy1) * 0.5f;
            float gw = gx1 - gx0, gh = gy1 - gy0;
            float e0 = ((gcx - pcx) / pw) * 10.f;
            float e1 = ((gcy - pcy) / ph) * 10.f;
            float e2 = logf(gw / pw) * 5.f;
            float e3 = logf(gh / ph) * 5.f;
            float d;
            d = fabsf(lp[4*k+0] - e0); sum += (d < 1.f) ? 0.5f*d*d : d - 0.5f;
            d = fabsf(lp[4*k+1] - e1); sum += (d < 1.f) ? 0.5f*d*d : d - 0.5f;
            d = fabsf(lp[4*k+2] - e2); sum += (d < 1.f) ? 0.5f*d*d : d - 0.5f;
            d = fabsf(lp[4*k+3] - e3); sum += (d < 1.f) ? 0.5f*d*d : d - 0.5f;
        }
        atomicAdd(llsum, sum);
    }
}

// ---------------- Kernel D: LDS-resident 4-level byte-histogram top-T select + CE sum ----------------
__global__ __launch_bounds__(256) void k_select(
    const unsigned* __restrict__ u, const float* __restrict__ ce,
    const int* __restrict__ npos,
    float* __restrict__ cesum, int* __restrict__ selc)
{
    int b = blockIdx.x, tid = threadIdx.x;
    const unsigned* ub = u + (size_t)b * NP;
    const float* ceb = ce + (size_t)b * NP;

    __shared__ unsigned su[NP];     // 33.6 KB
    __shared__ int hist[256];
    __shared__ int sc[256];
    __shared__ float sf[256];
    __shared__ unsigned s_prefix;
    __shared__ int s_remain;
    __shared__ int s_cutoff;

    for (int p = tid; p < NP; p += 256) su[p] = ub[p];
    int np = npos[b];
    int T = NPR * np;
    if (T > NP - np) T = NP - np;
    if (tid == 0) { s_prefix = 0u; s_remain = T; }
    __syncthreads();

    // 4 byte-levels, MSB first: find T-th largest key (exact)
#pragma unroll
    for (int level = 0; level < 4; ++level) {
        const int shift = 24 - 8 * level;
        hist[tid] = 0;
        __syncthreads();
        unsigned pref = s_prefix;
        int remain = s_remain;
        for (int p = tid; p < NP; p += 256) {
            unsigned v = su[p];
            bool match;
            if (level == 0) match = true;
            else match = ((v >> (shift + 8)) == pref);
            if (match) atomicAdd(&hist[(v >> shift) & 255], 1);
        }
        __syncthreads();
        int h = hist[tid];
        sc[tid] = h;
        __syncthreads();
        // inclusive suffix sum: sc[t] = sum_{j>=t} hist[j]
        for (int s = 1; s < 256; s <<= 1) {
            int add = (tid + s < 256) ? sc[tid + s] : 0;
            __syncthreads();
            sc[tid] += add;
            __syncthreads();
        }
        int above = (tid < 255) ? sc[tid + 1] : 0;
        if (above < remain && above + h >= remain) {    // exactly one thread
            s_prefix = (pref << 8) | (unsigned)tid;
            s_remain = remain - above;
        }
        __syncthreads();
    }
    unsigned thr = s_prefix;
    int needed = s_remain;   // boundary ties to take, ascending index order

    // count ties
    int tc = 0;
    for (int p = tid; p < NP; p += 256) tc += (su[p] == thr) ? 1 : 0;
    sc[tid] = tc;
    __syncthreads();
    for (int s = 128; s > 0; s >>= 1) { if (tid < s) sc[tid] += sc[tid + s]; __syncthreads(); }
    if (tid == 0) {
        int total_ties = sc[0];
        if (total_ties <= needed) s_cutoff = NP;     // take all ties
        else {                                        // rare: stable prefix by index
            int c2 = 0, cut = -1;
            for (int p = 0; p < NP; ++p)
                if (su[p] == thr) { if (++c2 == needed) { cut = p; break; } }
            s_cutoff = cut;
        }
    }
    __syncthreads();
    int cutoff = s_cutoff;

    // sum CE over positives (MARKER) + selected negatives
    float sum = 0.f;
    for (int p = tid; p < NP; p += 256) {
        unsigned v = su[p];
        bool take = (v == MARKER) || (v > thr) || ((v == thr) && (p <= cutoff));
        if (take) sum += ceb[p];
    }
    sf[tid] = sum;
    __syncthreads();
    for (int s = 128; s > 0; s >>= 1) { if (tid < s) sf[tid] += sf[tid + s]; __syncthreads(); }
    if (tid == 0) {
        atomicAdd(cesum, sf[0]);
        atomicAdd(selc, np + T);
    }
}

// ---------------- Kernel E: finalize ----------------
__global__ void k_final(const float* __restrict__ llsum, const int* __restrict__ Ntot,
                        const float* __restrict__ cesum, const int* __restrict__ selc,
                        float* __restrict__ out)
{
    if (blockIdx.x == 0 && threadIdx.x == 0) {
        out[0] = llsum[0] / (float)NK / (float)Ntot[0];
        out[1] = cesum[0] / (float)selc[0];
    }
}

extern "C" void kernel_launch(void* const* d_in, const int* in_sizes, int n_in,
                              void* d_out, int out_size, void* d_ws, size_t ws_size,
                              hipStream_t stream)
{
    const float* loc   = (const float*)d_in[0];
    const float* conf  = (const float*)d_in[1];
    const float* prior = (const float*)d_in[2];
    const float* gtr   = (const float*)d_in[3];
    float* out = (float*)d_out;

    char* w = (char*)d_ws;
    size_t bp = (size_t)NB * NP;
    float*    iou   = (float*)w;    w += bp * sizeof(float);
    unsigned* u     = (unsigned*)w; w += bp * sizeof(unsigned);
    float*    ce    = (float*)w;    w += bp * sizeof(float);
    // zero-initialized region (single memset): packed, cnt, llsum, cesum, selc
    unsigned long long* packed = (unsigned long long*)w; w += NB * sizeof(unsigned long long);
    int*   cnt   = (int*)w;   w += NB * sizeof(int);
    float* llsum = (float*)w; w += sizeof(float);
    float* cesum = (float*)w; w += sizeof(float);
    int*   selc  = (int*)w;   w += sizeof(int);
    size_t zbytes = (size_t)(w - (char*)packed);
    // non-initialized (always written before read)
    int* best = (int*)w; w += NB * sizeof(int);
    int* npos = (int*)w; w += NB * sizeof(int);
    int* Ntot = (int*)w; w += sizeof(int);

    hipMemsetAsync(packed, 0, zbytes, stream);

    dim3 g2((NP + 255) / 256, NB);
    k_iou   <<<g2, 256, 0, stream>>>(prior, gtr, iou, packed, cnt);
    k_mini  <<<1, 64, 0, stream>>>(packed, cnt, iou, best, npos, Ntot);
    k_conf  <<<g2, 256, 0, stream>>>(loc, conf, prior, gtr, iou, best, u, ce, llsum);
    k_select<<<NB, 256, 0, stream>>>(u, ce, npos, cesum, selc);
    k_final <<<1, 64, 0, stream>>>(llsum, Ntot, cesum, selc, out);
}